// Round 9
// baseline (17937.073 us; speedup 1.0000x reference)
//
#include <hip/hip_runtime.h>
#include <stdint.h>

typedef __attribute__((ext_vector_type(4))) float f32x4;
typedef __attribute__((ext_vector_type(8))) short s8v;
typedef __attribute__((ext_vector_type(4))) unsigned short u4v;
typedef __bf16 bf16x8 __attribute__((ext_vector_type(8)));
typedef unsigned long long ull;

#define DEV static __device__ __forceinline__

constexpr int Bb = 2, Tt = 2048, DE = 1024, Hh = 2048, NH = 16, KD = 128, VD = 128, Vv = 32000;
constexpr int QKVC = NH * (2 * KD + VD);   // 6144

DEV unsigned short f2bf(float x) {
    unsigned u = __builtin_bit_cast(unsigned, x);
    unsigned r = (u + 0x7fffu + ((u >> 16) & 1u)) >> 16;
    return (unsigned short)r;
}
DEV float bf2f(unsigned short b) {
    unsigned u = ((unsigned)b) << 16;
    return __builtin_bit_cast(float, u);
}
DEV bf16x8 as_bf(s8v v) { return __builtin_bit_cast(bf16x8, v); }

DEV void gll16(const void* g, void* l) {
    __builtin_amdgcn_global_load_lds((__attribute__((address_space(1))) void*)g,
                                     (__attribute__((address_space(3))) void*)l, 16, 0, 0);
}

// ---------------- fp32 -> bf16 convert ----------------
__global__ void k_cvt(const float* __restrict__ in, unsigned short* __restrict__ out, int n4) {
    int i = blockIdx.x * blockDim.x + threadIdx.x;
    if (i < n4) {
        float4 v = reinterpret_cast<const float4*>(in)[i];
        u4v o = {f2bf(v.x), f2bf(v.y), f2bf(v.z), f2bf(v.w)};
        reinterpret_cast<u4v*>(out)[i] = o;
    }
}

// ---------------- embedding gather + convert ----------------
__global__ void k_embed(const int* __restrict__ tok, const float* __restrict__ E,
                        unsigned short* __restrict__ x) {
    int bt = blockIdx.x;
    int t4 = threadIdx.x;   // 256 threads * 4 floats = 1024 = DE
    float4 v = reinterpret_cast<const float4*>(E + (size_t)tok[bt] * DE)[t4];
    u4v o = {f2bf(v.x), f2bf(v.y), f2bf(v.z), f2bf(v.w)};
    reinterpret_cast<u4v*>(x + (size_t)bt * DE)[t4] = o;
}

// ---------------- bf16 GEMM: C(MxN) = A(MxK) * Bw(NxK)^T + bias ----------------
template<int OUT_F32, int HAS_BIAS>
__global__ __launch_bounds__(256)
void k_gemm(const unsigned short* __restrict__ A, const unsigned short* __restrict__ Bw,
            const float* __restrict__ bias, void* __restrict__ Cv,
            int M, int N, int K) {
    __shared__ unsigned short As[128 * 32];
    __shared__ unsigned short Bs[128 * 32];
    const int tid = threadIdx.x;
    const int lane = tid & 63, wave = tid >> 6;
    const int wr = wave >> 1, wc = wave & 1;
    const int l15 = lane & 15, l16 = lane >> 4;
    const int m0 = blockIdx.y * 128, n0 = blockIdx.x * 128;

    f32x4 acc[4][4] = {};

    const int srow = tid >> 2, schunk = tid & 3;
    const unsigned short* gA = A + (size_t)(m0 + srow) * K + schunk * 8;
    const unsigned short* gB = Bw + (size_t)(n0 + srow) * K + schunk * 8;
    unsigned short* ldsA0 = As + wave * 512;
    unsigned short* ldsA1 = As + 2048 + wave * 512;
    unsigned short* ldsB0 = Bs + wave * 512;
    unsigned short* ldsB1 = Bs + 2048 + wave * 512;
    const size_t rs64 = (size_t)64 * K;

    for (int kt = 0; kt < K; kt += 32) {
        gll16(gA + kt, ldsA0);
        gll16(gA + rs64 + kt, ldsA1);
        gll16(gB + kt, ldsB0);
        gll16(gB + rs64 + kt, ldsB1);
        __syncthreads();
        s8v af[4], bfv[4];
        #pragma unroll
        for (int m = 0; m < 4; ++m)
            af[m] = *reinterpret_cast<const s8v*>(As + (wr * 64 + m * 16 + l15) * 32 + l16 * 8);
        #pragma unroll
        for (int n = 0; n < 4; ++n)
            bfv[n] = *reinterpret_cast<const s8v*>(Bs + (wc * 64 + n * 16 + l15) * 32 + l16 * 8);
        #pragma unroll
        for (int m = 0; m < 4; ++m)
            #pragma unroll
            for (int n = 0; n < 4; ++n)
                acc[m][n] = __builtin_amdgcn_mfma_f32_16x16x32_bf16(as_bf(af[m]), as_bf(bfv[n]), acc[m][n], 0, 0, 0);
        __syncthreads();
    }

    #pragma unroll
    for (int m = 0; m < 4; ++m) {
        const int r0 = m0 + wr * 64 + m * 16 + l16 * 4;
        #pragma unroll
        for (int n = 0; n < 4; ++n) {
            const int c = n0 + wc * 64 + n * 16 + l15;
            const float bv = HAS_BIAS ? bias[c] : 0.0f;
            #pragma unroll
            for (int j = 0; j < 4; ++j) {
                float v = acc[m][n][j] + bv;
                if (OUT_F32) ((float*)Cv)[(size_t)(r0 + j) * N + c] = v;
                else ((unsigned short*)Cv)[(size_t)(r0 + j) * N + c] = f2bf(v);
            }
        }
    }
}

// ---------------- persistent RNN scan (fence-free sentinel data-flow) ----------------
// h_t = gelu(xi_t + Wh h_{t-1}).
// r8 post-mortem: step time = weight L2->L1 re-stream (1.67us) + IC visibility.
// Fix: weights LDS-RESIDENT as bf16 (loaded once; r7 proved LDS-weights work, its
// failure was 512-WG fan-out). 256 WGs x 512 thr; ONE WAVE = ONE COLUMN
// (col = wg*8 + wave), both batches per WG -> Wh device-read exactly once.
// LDS: 32KB bf16 weights + 32KB fp32 h double-buffer = 64KB static (r7-proven size).
// Cross-WG h via write-once hseq[t][b][col] fp32, sentinel 0xFFFFFFFF, relaxed
// agent-scope atomics only (no fences, no L2 writeback/invalidate); r2 poll layout.
__global__ __launch_bounds__(512)
void k_scan(const float* __restrict__ Wh, const float* __restrict__ xi,
            unsigned short* __restrict__ hs, float* __restrict__ hseq) {
    const int wg = blockIdx.x;          // 0..255
    const int tid = threadIdx.x;
    const int lane = tid & 63, wave = tid >> 6;
    const int col = wg * 8 + wave;      // this wave's output column

    __shared__ unsigned short wlds[8][Hh];  // bf16 weights, 32KB, written once
    __shared__ float hsh[2][2][Hh];         // [parity][batch][k] fp32, 32KB

    // stage weights once: row r, this thread's f32x4 at tid*4 (coalesced)
    #pragma unroll
    for (int r = 0; r < 8; ++r) {
        f32x4 v = *reinterpret_cast<const f32x4*>(Wh + ((size_t)wg * 8 + r) * Hh + tid * 4);
        u4v o = {f2bf(v[0]), f2bf(v[1]), f2bf(v[2]), f2bf(v[3])};
        *reinterpret_cast<u4v*>(&wlds[r][tid * 4]) = o;
    }
    for (int i = tid; i < 2 * Hh; i += 512) { hsh[0][0][i] = 0.0f; hsh[1][0][i] = 0.0f; }
    __syncthreads();

    for (int t = 0; t < Tt; ++t) {
        // xi for this wave's column, both batches (lane 0 only uses them)
        float xv0 = 0.0f, xv1 = 0.0f;
        if (lane == 0) {
            xv0 = xi[(size_t)t * Hh + col];
            xv1 = xi[((size_t)Tt + t) * Hh + col];
        }
        const float* hb0 = &hsh[t & 1][0][0];
        const float* hb1 = &hsh[t & 1][1][0];
        f32x4 a0 = {}, a1 = {};
        #pragma unroll
        for (int i = 0; i < 8; ++i) {
            // 4 bf16 weights (8B ds_read), unpack via shift/mask (exact)
            uint2 wu = *reinterpret_cast<const uint2*>(&wlds[wave][lane * 4 + i * 256]);
            f32x4 wv;
            wv[0] = __builtin_bit_cast(float, wu.x << 16);
            wv[1] = __builtin_bit_cast(float, wu.x & 0xffff0000u);
            wv[2] = __builtin_bit_cast(float, wu.y << 16);
            wv[3] = __builtin_bit_cast(float, wu.y & 0xffff0000u);
            const f32x4 h0 = *reinterpret_cast<const f32x4*>(hb0 + lane * 4 + i * 256);
            const f32x4 h1 = *reinterpret_cast<const f32x4*>(hb1 + lane * 4 + i * 256);
            a0 += wv * h0;
            a1 += wv * h1;
        }
        float s0 = a0[0] + a0[1] + a0[2] + a0[3];
        float s1 = a1[0] + a1[1] + a1[2] + a1[3];
        #pragma unroll
        for (int d = 32; d >= 1; d >>= 1) {
            s0 += __shfl_xor(s0, d);
            s1 += __shfl_xor(s1, d);
        }
        if (lane == 0) {
            float A0 = xv0 + s0, A1 = xv1 + s1;
            float h0 = 0.5f * A0 * (1.0f + erff(A0 * 0.70710678118654752f));
            float h1 = 0.5f * A1 * (1.0f + erff(A1 * 0.70710678118654752f));
            __hip_atomic_store(hseq + ((size_t)t * 2 + 0) * Hh + col, h0,
                               __ATOMIC_RELAXED, __HIP_MEMORY_SCOPE_AGENT);
            __hip_atomic_store(hseq + ((size_t)t * 2 + 1) * Hh + col, h1,
                               __ATOMIC_RELAXED, __HIP_MEMORY_SCOPE_AGENT);
            hs[(size_t)t * Hh + col]          = f2bf(h0);
            hs[((size_t)Tt + t) * Hh + col]   = f2bf(h1);
        }
        if (t + 1 < Tt) {
            // poll full h_t (both batches, 16KB); r2 conflict-free layout
            const ull* p0 = reinterpret_cast<const ull*>(hseq + (size_t)t * 2 * Hh);
            ull v0 = __hip_atomic_load(p0 + tid,        __ATOMIC_RELAXED, __HIP_MEMORY_SCOPE_AGENT);
            ull v1 = __hip_atomic_load(p0 + 512 + tid,  __ATOMIC_RELAXED, __HIP_MEMORY_SCOPE_AGENT);
            ull v2 = __hip_atomic_load(p0 + 1024 + tid, __ATOMIC_RELAXED, __HIP_MEMORY_SCOPE_AGENT);
            ull v3 = __hip_atomic_load(p0 + 1536 + tid, __ATOMIC_RELAXED, __HIP_MEMORY_SCOPE_AGENT);
            auto bad = [](ull v) -> bool {
                return ((unsigned)v == 0xFFFFFFFFu) || ((unsigned)(v >> 32) == 0xFFFFFFFFu);
            };
            bool n0 = bad(v0), n1 = bad(v1), n2 = bad(v2), n3 = bad(v3);
            int spins = 0;
            while (n0 | n1 | n2 | n3) {
                if (n0) { v0 = __hip_atomic_load(p0 + tid,        __ATOMIC_RELAXED, __HIP_MEMORY_SCOPE_AGENT); n0 = bad(v0); }
                if (n1) { v1 = __hip_atomic_load(p0 + 512 + tid,  __ATOMIC_RELAXED, __HIP_MEMORY_SCOPE_AGENT); n1 = bad(v1); }
                if (n2) { v2 = __hip_atomic_load(p0 + 1024 + tid, __ATOMIC_RELAXED, __HIP_MEMORY_SCOPE_AGENT); n2 = bad(v2); }
                if (n3) { v3 = __hip_atomic_load(p0 + 1536 + tid, __ATOMIC_RELAXED, __HIP_MEMORY_SCOPE_AGENT); n3 = bad(v3); }
                if (++spins > (1 << 24)) break;   // anti-hang insurance
            }
            ull* bufW = reinterpret_cast<ull*>(&hsh[(t + 1) & 1][0][0]);
            bufW[tid]        = v0;
            bufW[512 + tid]  = v1;
            bufW[1024 + tid] = v2;
            bufW[1536 + tid] = v3;
            __syncthreads();
        }
    }
}

// ---------------- causal flash attention ----------------
__global__ __launch_bounds__(256)
void k_attn(const unsigned short* __restrict__ qkv, unsigned short* __restrict__ ao) {
    const int tid = threadIdx.x;
    const int lane = tid & 63, wave = tid >> 6;
    const int l15 = lane & 15, l16 = lane >> 4;
    const int qt = blockIdx.x, bh = blockIdx.y;
    const int b = bh >> 4, hh = bh & 15;

    __shared__ unsigned short Ks[64][136];
    __shared__ unsigned short Vt[128][72];
    __shared__ unsigned short Ps[4][16][72];

    const int qr0 = qt * 64 + wave * 16;
    const unsigned short* qbase = qkv + (size_t)(b * Tt + qr0 + l15) * QKVC + hh * KD;
    s8v qf[4];
    #pragma unroll
    for (int kc = 0; kc < 4; ++kc)
        qf[kc] = *reinterpret_cast<const s8v*>(qbase + kc * 32 + l16 * 8);

    f32x4 o[8] = {};
    float mrow[4] = {-3e38f, -3e38f, -3e38f, -3e38f};
    float lrow[4] = {0.f, 0.f, 0.f, 0.f};

    const int kvend = qt * 64 + 64;
    for (int kv0 = 0; kv0 < kvend; kv0 += 64) {
        __syncthreads();
        {
            const int r = tid >> 4, c = tid & 15;
            #pragma unroll
            for (int p = 0; p < 4; ++p) {
                int row = r + p * 16;
                const unsigned short* src = qkv + (size_t)(b * Tt + kv0 + row) * QKVC + hh * KD;
                s8v kv8 = *reinterpret_cast<const s8v*>(src + NH * KD + c * 8);
                *reinterpret_cast<s8v*>(&Ks[row][c * 8]) = kv8;
                s8v vv8 = *reinterpret_cast<const s8v*>(src + 2 * NH * KD + c * 8);
                #pragma unroll
                for (int i = 0; i < 8; ++i)
                    Vt[c * 8 + i][row] = (unsigned short)vv8[i];
            }
        }
        __syncthreads();
        f32x4 s[4] = {};
        #pragma unroll
        for (int kc = 0; kc < 4; ++kc) {
            #pragma unroll
            for (int nf = 0; nf < 4; ++nf) {
                s8v kf = *reinterpret_cast<const s8v*>(&Ks[nf * 16 + l15][kc * 32 + l16 * 8]);
                s[nf] = __builtin_amdgcn_mfma_f32_16x16x32_bf16(as_bf(qf[kc]), as_bf(kf), s[nf], 0, 0, 0);
            }
        }
        const float sc = 0.088388347648318447f;   // 1/sqrt(128)
        #pragma unroll
        for (int nf = 0; nf < 4; ++nf)
            #pragma unroll
            for (int jj = 0; jj < 4; ++jj) {
                int col = kv0 + nf * 16 + l15;
                int row = qr0 + l16 * 4 + jj;
                s[nf][jj] = (col <= row) ? s[nf][jj] * sc : -3e38f;
            }
        #pragma unroll
        for (int jj = 0; jj < 4; ++jj) {
            float vm = fmaxf(fmaxf(s[0][jj], s[1][jj]), fmaxf(s[2][jj], s[3][jj]));
            vm = fmaxf(vm, __shfl_xor(vm, 1));
            vm = fmaxf(vm, __shfl_xor(vm, 2));
            vm = fmaxf(vm, __shfl_xor(vm, 4));
            vm = fmaxf(vm, __shfl_xor(vm, 8));
            float mn = fmaxf(mrow[jj], vm);
            float scale = __expf(mrow[jj] - mn);
            float ps = 0.f;
            #pragma unroll
            for (int nf = 0; nf < 4; ++nf) {
                float p = __expf(s[nf][jj] - mn);
                s[nf][jj] = p;
                ps += p;
            }
            ps += __shfl_xor(ps, 1); ps += __shfl_xor(ps, 2);
            ps += __shfl_xor(ps, 4); ps += __shfl_xor(ps, 8);
            lrow[jj] = lrow[jj] * scale + ps;
            mrow[jj] = mn;
            #pragma unroll
            for (int nf = 0; nf < 8; ++nf) o[nf][jj] *= scale;
        }
        #pragma unroll
        for (int nf = 0; nf < 4; ++nf)
            #pragma unroll
            for (int jj = 0; jj < 4; ++jj)
                Ps[wave][l16 * 4 + jj][nf * 16 + l15] = f2bf(s[nf][jj]);
        __syncthreads();
        #pragma unroll
        for (int kc = 0; kc < 2; ++kc) {
            s8v pf = *reinterpret_cast<const s8v*>(&Ps[wave][l15][kc * 32 + l16 * 8]);
            #pragma unroll
            for (int nf = 0; nf < 8; ++nf) {
                s8v vf = *reinterpret_cast<const s8v*>(&Vt[nf * 16 + l15][kc * 32 + l16 * 8]);
                o[nf] = __builtin_amdgcn_mfma_f32_16x16x32_bf16(as_bf(pf), as_bf(vf), o[nf], 0, 0, 0);
            }
        }
    }
    #pragma unroll
    for (int nf = 0; nf < 8; ++nf)
        #pragma unroll
        for (int jj = 0; jj < 4; ++jj) {
            float v = o[nf][jj] / lrow[jj];
            ao[(size_t)(b * Tt + qr0 + l16 * 4 + jj) * Hh + hh * VD + nf * 16 + l15] = f2bf(v);
        }
}

// ---------------- residual + LayerNorm ----------------
__global__ __launch_bounds__(256)
void k_ln(const unsigned short* __restrict__ aop, const unsigned short* __restrict__ rnn,
          const float* __restrict__ g, const float* __restrict__ be,
          unsigned short* __restrict__ y) {
    const int row = blockIdx.x, tid = threadIdx.x;
    const int lane = tid & 63, wave = tid >> 6;
    const size_t base = (size_t)row * Hh;
    s8v a8 = *reinterpret_cast<const s8v*>(aop + base + tid * 8);
    s8v r8 = *reinterpret_cast<const s8v*>(rnn + base + tid * 8);
    float v[8]; float s = 0.f;
    #pragma unroll
    for (int i = 0; i < 8; ++i) {
        v[i] = bf2f((unsigned short)a8[i]) + bf2f((unsigned short)r8[i]);
        s += v[i];
    }
    #pragma unroll
    for (int d = 32; d >= 1; d >>= 1) s += __shfl_xor(s, d);
    __shared__ float red[8];
    if (lane == 0) red[wave] = s;
    __syncthreads();
    float mu = (red[0] + red[1] + red[2] + red[3]) * (1.0f / Hh);
    float d2 = 0.f;
    #pragma unroll
    for (int i = 0; i < 8; ++i) { float dd = v[i] - mu; d2 += dd * dd; }
    #pragma unroll
    for (int d = 32; d >= 1; d >>= 1) d2 += __shfl_xor(d2, d);
    if (lane == 0) red[4 + wave] = d2;
    __syncthreads();
    float var = (red[4] + red[5] + red[6] + red[7]) * (1.0f / Hh);
    float rstd = rsqrtf(var + 1e-5f);
    s8v outv;
    #pragma unroll
    for (int i = 0; i < 8; ++i) {
        int c = tid * 8 + i;
        float ov = (v[i] - mu) * rstd * g[c] + be[c];
        outv[i] = (short)f2bf(ov);
    }
    *reinterpret_cast<s8v*>(y + base + tid * 8) = outv;
}

extern "C" void kernel_launch(void* const* d_in, const int* in_sizes, int n_in,
                              void* d_out, int out_size, void* d_ws, size_t ws_size,
                              hipStream_t stream) {
    const int*   tokens = (const int*)  d_in[0];
    const float* E    = (const float*)d_in[1];
    const float* Wi   = (const float*)d_in[2];
    const float* bi   = (const float*)d_in[3];
    const float* Wh   = (const float*)d_in[4];
    const float* Wo   = (const float*)d_in[5];
    const float* bo   = (const float*)d_in[6];
    const float* Wqkv = (const float*)d_in[7];
    const float* Wao  = (const float*)d_in[8];
    const float* bao  = (const float*)d_in[9];
    const float* lng  = (const float*)d_in[10];
    const float* lnb  = (const float*)d_in[11];
    const float* Wlm  = (const float*)d_in[12];
    const float* blm  = (const float*)d_in[13];
    float* out = (float*)d_out;

    char* ws = (char*)d_ws;
    size_t off = 0;
    auto alloc = [&](size_t bytes) -> void* {
        void* p = ws + off;
        off += (bytes + 255) & ~(size_t)255;
        return p;
    };
    unsigned short* bWi   = (unsigned short*)alloc((size_t)Hh * DE * 2);
    unsigned short* bWo   = (unsigned short*)alloc((size_t)Hh * Hh * 2);
    unsigned short* bWqkv = (unsigned short*)alloc((size_t)QKVC * Hh * 2);
    unsigned short* bWao  = (unsigned short*)alloc((size_t)Hh * Hh * 2);
    unsigned short* bWlm  = (unsigned short*)alloc((size_t)Vv * Hh * 2);
    unsigned short* xb    = (unsigned short*)alloc((size_t)Bb * Tt * DE * 2);
    float*          xi    = (float*)         alloc((size_t)Bb * Tt * Hh * 4);
    unsigned short* hsb   = (unsigned short*)alloc((size_t)Bb * Tt * Hh * 2);
    unsigned short* rnn   = (unsigned short*)alloc((size_t)Bb * Tt * Hh * 2);
    unsigned short* qkvb  = (unsigned short*)alloc((size_t)Bb * Tt * QKVC * 2);
    unsigned short* aob   = (unsigned short*)alloc((size_t)Bb * Tt * Hh * 2);
    unsigned short* aopb  = (unsigned short*)alloc((size_t)Bb * Tt * Hh * 2);
    unsigned short* yb    = (unsigned short*)alloc((size_t)Bb * Tt * Hh * 2);

    // hseq (32MB, write-once per step) aliases qkvb's space: qkvb (50MB) is
    // only written by the qkv GEMM, which runs strictly after k_scan completes.
    float* hseq = (float*)qkvb;
    hipMemsetAsync(hseq, 0xFF, (size_t)Tt * 2 * Hh * 4, stream);   // sentinel poison

    auto cvt = [&](const float* src, unsigned short* dst, size_t n) {
        int n4 = (int)(n / 4);
        k_cvt<<<(n4 + 255) / 256, 256, 0, stream>>>(src, dst, n4);
    };
    cvt(Wi,   bWi,   (size_t)Hh * DE);
    cvt(Wo,   bWo,   (size_t)Hh * Hh);
    cvt(Wqkv, bWqkv, (size_t)QKVC * Hh);
    cvt(Wao,  bWao,  (size_t)Hh * Hh);
    cvt(Wlm,  bWlm,  (size_t)Vv * Hh);

    k_embed<<<Bb * Tt, 256, 0, stream>>>(tokens, E, xb);

    // xi = x @ Wi^T + bi   (fp32 out)
    k_gemm<1, 1><<<dim3(Hh / 128, (Bb * Tt) / 128), 256, 0, stream>>>(xb, bWi, bi, xi, Bb * Tt, Hh, DE);
    // sequential RNN scan -> hs (bf16)
    k_scan<<<256, 512, 0, stream>>>(Wh, xi, hsb, hseq);
    // rnn_out = hs @ Wo^T + bo  (bf16)
    k_gemm<0, 1><<<dim3(Hh / 128, (Bb * Tt) / 128), 256, 0, stream>>>(hsb, bWo, bo, rnn, Bb * Tt, Hh, Hh);
    // qkv = rnn_out @ Wqkv^T    (bf16, no bias)
    k_gemm<0, 0><<<dim3(QKVC / 128, (Bb * Tt) / 128), 256, 0, stream>>>(rnn, bWqkv, nullptr, qkvb, Bb * Tt, QKVC, Hh);
    // causal attention
    k_attn<<<dim3(Tt / 64, Bb * NH), 256, 0, stream>>>(qkvb, aob);
    // ao @ Wao^T + bao          (bf16)
    k_gemm<0, 1><<<dim3(Hh / 128, (Bb * Tt) / 128), 256, 0, stream>>>(aob, bWao, bao, aopb, Bb * Tt, Hh, Hh);
    // y = LN(aop + rnn_out)
    k_ln<<<Bb * Tt, 256, 0, stream>>>(aopb, rnn, lng, lnb, yb);
    // logits = y @ Wlm^T + blm  (fp32 out)
    k_gemm<1, 1><<<dim3(Vv / 128, (Bb * Tt) / 128), 256, 0, stream>>>(yb, bWlm, blm, out, Bb * Tt, Vv, Hh);
}

// Round 10
// 6382.263 us; speedup vs baseline: 2.8105x; 2.8105x over previous
//
#include <hip/hip_runtime.h>
#include <stdint.h>

typedef __attribute__((ext_vector_type(4))) float f32x4;
typedef __attribute__((ext_vector_type(8))) short s8v;
typedef __attribute__((ext_vector_type(4))) unsigned short u4v;
typedef __attribute__((ext_vector_type(4))) unsigned int u32x4;
typedef __bf16 bf16x8 __attribute__((ext_vector_type(8)));
typedef unsigned long long ull;

#define DEV static __device__ __forceinline__

constexpr int Bb = 2, Tt = 2048, DE = 1024, Hh = 2048, NH = 16, KD = 128, VD = 128, Vv = 32000;
constexpr int QKVC = NH * (2 * KD + VD);   // 6144

DEV unsigned short f2bf(float x) {
    unsigned u = __builtin_bit_cast(unsigned, x);
    unsigned r = (u + 0x7fffu + ((u >> 16) & 1u)) >> 16;
    return (unsigned short)r;
}
DEV float bf2f(unsigned short b) {
    unsigned u = ((unsigned)b) << 16;
    return __builtin_bit_cast(float, u);
}
DEV bf16x8 as_bf(s8v v) { return __builtin_bit_cast(bf16x8, v); }

DEV void gll16(const void* g, void* l) {
    __builtin_amdgcn_global_load_lds((__attribute__((address_space(1))) void*)g,
                                     (__attribute__((address_space(3))) void*)l, 16, 0, 0);
}

// ---------------- fp32 -> bf16 convert ----------------
__global__ void k_cvt(const float* __restrict__ in, unsigned short* __restrict__ out, int n4) {
    int i = blockIdx.x * blockDim.x + threadIdx.x;
    if (i < n4) {
        float4 v = reinterpret_cast<const float4*>(in)[i];
        u4v o = {f2bf(v.x), f2bf(v.y), f2bf(v.z), f2bf(v.w)};
        reinterpret_cast<u4v*>(out)[i] = o;
    }
}

// ---------------- embedding gather + convert ----------------
__global__ void k_embed(const int* __restrict__ tok, const float* __restrict__ E,
                        unsigned short* __restrict__ x) {
    int bt = blockIdx.x;
    int t4 = threadIdx.x;   // 256 threads * 4 floats = 1024 = DE
    float4 v = reinterpret_cast<const float4*>(E + (size_t)tok[bt] * DE)[t4];
    u4v o = {f2bf(v.x), f2bf(v.y), f2bf(v.z), f2bf(v.w)};
    reinterpret_cast<u4v*>(x + (size_t)bt * DE)[t4] = o;
}

// ---------------- bf16 GEMM: C(MxN) = A(MxK) * Bw(NxK)^T + bias ----------------
template<int OUT_F32, int HAS_BIAS>
__global__ __launch_bounds__(256)
void k_gemm(const unsigned short* __restrict__ A, const unsigned short* __restrict__ Bw,
            const float* __restrict__ bias, void* __restrict__ Cv,
            int M, int N, int K) {
    __shared__ unsigned short As[128 * 32];
    __shared__ unsigned short Bs[128 * 32];
    const int tid = threadIdx.x;
    const int lane = tid & 63, wave = tid >> 6;
    const int wr = wave >> 1, wc = wave & 1;
    const int l15 = lane & 15, l16 = lane >> 4;
    const int m0 = blockIdx.y * 128, n0 = blockIdx.x * 128;

    f32x4 acc[4][4] = {};

    const int srow = tid >> 2, schunk = tid & 3;
    const unsigned short* gA = A + (size_t)(m0 + srow) * K + schunk * 8;
    const unsigned short* gB = Bw + (size_t)(n0 + srow) * K + schunk * 8;
    unsigned short* ldsA0 = As + wave * 512;
    unsigned short* ldsA1 = As + 2048 + wave * 512;
    unsigned short* ldsB0 = Bs + wave * 512;
    unsigned short* ldsB1 = Bs + 2048 + wave * 512;
    const size_t rs64 = (size_t)64 * K;

    for (int kt = 0; kt < K; kt += 32) {
        gll16(gA + kt, ldsA0);
        gll16(gA + rs64 + kt, ldsA1);
        gll16(gB + kt, ldsB0);
        gll16(gB + rs64 + kt, ldsB1);
        __syncthreads();
        s8v af[4], bfv[4];
        #pragma unroll
        for (int m = 0; m < 4; ++m)
            af[m] = *reinterpret_cast<const s8v*>(As + (wr * 64 + m * 16 + l15) * 32 + l16 * 8);
        #pragma unroll
        for (int n = 0; n < 4; ++n)
            bfv[n] = *reinterpret_cast<const s8v*>(Bs + (wc * 64 + n * 16 + l15) * 32 + l16 * 8);
        #pragma unroll
        for (int m = 0; m < 4; ++m)
            #pragma unroll
            for (int n = 0; n < 4; ++n)
                acc[m][n] = __builtin_amdgcn_mfma_f32_16x16x32_bf16(as_bf(af[m]), as_bf(bfv[n]), acc[m][n], 0, 0, 0);
        __syncthreads();
    }

    #pragma unroll
    for (int m = 0; m < 4; ++m) {
        const int r0 = m0 + wr * 64 + m * 16 + l16 * 4;
        #pragma unroll
        for (int n = 0; n < 4; ++n) {
            const int c = n0 + wc * 64 + n * 16 + l15;
            const float bv = HAS_BIAS ? bias[c] : 0.0f;
            #pragma unroll
            for (int j = 0; j < 4; ++j) {
                float v = acc[m][n][j] + bv;
                if (OUT_F32) ((float*)Cv)[(size_t)(r0 + j) * N + c] = v;
                else ((unsigned short*)Cv)[(size_t)(r0 + j) * N + c] = f2bf(v);
            }
        }
    }
}

// ---------------- persistent RNN scan (fence-free sentinel data-flow) ----------------
// h_t = gelu(xi_t + Wh h_{t-1}).
// r2/r8-proven geometry: 128 WGs x 512 thr; WG = 32 cols of ONE chain (wg>>6 = batch).
// Thread (g=tid>>4 col, kp=tid&15). NEW vs r8: weights are bf16 REGISTER-RESIDENT --
// 128 bf16 = 16 s8v = 64 packed VGPRs, pinned against rematerialization/sinking by
// an opaque `asm volatile("" : "+v")` every iteration (r3-r6 lesson: the allocator
// sinks/spills any large loop-invariant register set unless an instruction it
// cannot analyze claims to modify it). This removes r8's ~1.7us/step weight stream.
// h stays fp32. Cross-WG h via write-once hseq[t][b][col], sentinel 0xFFFFFFFF,
// relaxed agent-scope atomics only; r2 conflict-free poll/LDS layout.
__global__ __launch_bounds__(512)
void k_scan(const unsigned short* __restrict__ bWh, const float* __restrict__ xi,
            unsigned short* __restrict__ hs, float* __restrict__ hseq) {
    const int wg = blockIdx.x;          // 0..127
    const int tid = threadIdx.x;
    const int bsel = wg >> 6;           // chain / batch
    const int g = tid >> 4;             // col 0..31
    const int kp = tid & 15;            // k partition 0..15
    const int col = (wg & 63) * 32 + g;

    __shared__ float hsh[2][Hh];        // [parity][k] fp32, 16KB

    // weight slice: k = kp*8 + j + i*128, j<8, i<16  (16 x 16B contiguous loads)
    s8v w[16];
    const unsigned short* wrow = bWh + (size_t)col * Hh + kp * 8;
    #pragma unroll
    for (int i = 0; i < 16; ++i)
        w[i] = *reinterpret_cast<const s8v*>(wrow + i * 128);

    for (int i = tid; i < Hh; i += 512) { hsh[0][i] = 0.0f; hsh[1][i] = 0.0f; }
    __syncthreads();

    const size_t xcol = (size_t)bsel * Tt * Hh + col;

    for (int t = 0; t < Tt; ++t) {
        // pin W: opaque asm -> compiler must keep values live in VGPRs, cannot
        // re-execute the global loads (it must assume the asm modified them).
        #pragma unroll
        for (int i = 0; i < 16; ++i)
            asm volatile("" : "+v"(w[i]));

        float xv = 0.0f;
        if (kp == 0) xv = xi[xcol + (size_t)t * Hh];

        const float* hb = hsh[t & 1];
        f32x4 a4 = {};
        #pragma unroll
        for (int i = 0; i < 16; ++i) {
            const f32x4 h0 = *reinterpret_cast<const f32x4*>(hb + kp * 8 + i * 128);
            const f32x4 h1 = *reinterpret_cast<const f32x4*>(hb + kp * 8 + i * 128 + 4);
            u32x4 wu = __builtin_bit_cast(u32x4, w[i]);
            f32x4 wa, wb;
            wa[0] = __builtin_bit_cast(float, wu[0] << 16);
            wa[1] = __builtin_bit_cast(float, wu[0] & 0xffff0000u);
            wa[2] = __builtin_bit_cast(float, wu[1] << 16);
            wa[3] = __builtin_bit_cast(float, wu[1] & 0xffff0000u);
            wb[0] = __builtin_bit_cast(float, wu[2] << 16);
            wb[1] = __builtin_bit_cast(float, wu[2] & 0xffff0000u);
            wb[2] = __builtin_bit_cast(float, wu[3] << 16);
            wb[3] = __builtin_bit_cast(float, wu[3] & 0xffff0000u);
            a4 += wa * h0;
            a4 += wb * h1;
        }
        float s = a4[0] + a4[1] + a4[2] + a4[3];
        s += __shfl_xor(s, 8);
        s += __shfl_xor(s, 4);
        s += __shfl_xor(s, 2);
        s += __shfl_xor(s, 1);
        if (kp == 0) {
            float a = xv + s;
            float h = 0.5f * a * (1.0f + erff(a * 0.70710678118654752f));
            __hip_atomic_store(hseq + ((size_t)t * 2 + bsel) * Hh + col, h,
                               __ATOMIC_RELAXED, __HIP_MEMORY_SCOPE_AGENT);
            hs[((size_t)bsel * Tt + t) * Hh + col] = f2bf(h);
        }
        if (t + 1 < Tt) {
            // poll own chain's h_t (8KB/WG, 2 ull/thread); r2 conflict-free layout
            const ull* p0 = reinterpret_cast<const ull*>(hseq + ((size_t)t * 2 + bsel) * Hh);
            ull v0 = __hip_atomic_load(p0 + tid,       __ATOMIC_RELAXED, __HIP_MEMORY_SCOPE_AGENT);
            ull v1 = __hip_atomic_load(p0 + 512 + tid, __ATOMIC_RELAXED, __HIP_MEMORY_SCOPE_AGENT);
            auto bad = [](ull v) -> bool {
                return ((unsigned)v == 0xFFFFFFFFu) || ((unsigned)(v >> 32) == 0xFFFFFFFFu);
            };
            bool n0 = bad(v0), n1 = bad(v1);
            int spins = 0;
            while (n0 | n1) {
                if (n0) { v0 = __hip_atomic_load(p0 + tid,       __ATOMIC_RELAXED, __HIP_MEMORY_SCOPE_AGENT); n0 = bad(v0); }
                if (n1) { v1 = __hip_atomic_load(p0 + 512 + tid, __ATOMIC_RELAXED, __HIP_MEMORY_SCOPE_AGENT); n1 = bad(v1); }
                if (++spins > (1 << 24)) break;   // anti-hang insurance
            }
            ull* bufW = reinterpret_cast<ull*>(hsh[(t + 1) & 1]);
            bufW[tid]       = v0;
            bufW[512 + tid] = v1;
            __syncthreads();
        }
    }
}

// ---------------- causal flash attention ----------------
__global__ __launch_bounds__(256)
void k_attn(const unsigned short* __restrict__ qkv, unsigned short* __restrict__ ao) {
    const int tid = threadIdx.x;
    const int lane = tid & 63, wave = tid >> 6;
    const int l15 = lane & 15, l16 = lane >> 4;
    const int qt = blockIdx.x, bh = blockIdx.y;
    const int b = bh >> 4, hh = bh & 15;

    __shared__ unsigned short Ks[64][136];
    __shared__ unsigned short Vt[128][72];
    __shared__ unsigned short Ps[4][16][72];

    const int qr0 = qt * 64 + wave * 16;
    const unsigned short* qbase = qkv + (size_t)(b * Tt + qr0 + l15) * QKVC + hh * KD;
    s8v qf[4];
    #pragma unroll
    for (int kc = 0; kc < 4; ++kc)
        qf[kc] = *reinterpret_cast<const s8v*>(qbase + kc * 32 + l16 * 8);

    f32x4 o[8] = {};
    float mrow[4] = {-3e38f, -3e38f, -3e38f, -3e38f};
    float lrow[4] = {0.f, 0.f, 0.f, 0.f};

    const int kvend = qt * 64 + 64;
    for (int kv0 = 0; kv0 < kvend; kv0 += 64) {
        __syncthreads();
        {
            const int r = tid >> 4, c = tid & 15;
            #pragma unroll
            for (int p = 0; p < 4; ++p) {
                int row = r + p * 16;
                const unsigned short* src = qkv + (size_t)(b * Tt + kv0 + row) * QKVC + hh * KD;
                s8v kv8 = *reinterpret_cast<const s8v*>(src + NH * KD + c * 8);
                *reinterpret_cast<s8v*>(&Ks[row][c * 8]) = kv8;
                s8v vv8 = *reinterpret_cast<const s8v*>(src + 2 * NH * KD + c * 8);
                #pragma unroll
                for (int i = 0; i < 8; ++i)
                    Vt[c * 8 + i][row] = (unsigned short)vv8[i];
            }
        }
        __syncthreads();
        f32x4 s[4] = {};
        #pragma unroll
        for (int kc = 0; kc < 4; ++kc) {
            #pragma unroll
            for (int nf = 0; nf < 4; ++nf) {
                s8v kf = *reinterpret_cast<const s8v*>(&Ks[nf * 16 + l15][kc * 32 + l16 * 8]);
                s[nf] = __builtin_amdgcn_mfma_f32_16x16x32_bf16(as_bf(qf[kc]), as_bf(kf), s[nf], 0, 0, 0);
            }
        }
        const float sc = 0.088388347648318447f;   // 1/sqrt(128)
        #pragma unroll
        for (int nf = 0; nf < 4; ++nf)
            #pragma unroll
            for (int jj = 0; jj < 4; ++jj) {
                int col = kv0 + nf * 16 + l15;
                int row = qr0 + l16 * 4 + jj;
                s[nf][jj] = (col <= row) ? s[nf][jj] * sc : -3e38f;
            }
        #pragma unroll
        for (int jj = 0; jj < 4; ++jj) {
            float vm = fmaxf(fmaxf(s[0][jj], s[1][jj]), fmaxf(s[2][jj], s[3][jj]));
            vm = fmaxf(vm, __shfl_xor(vm, 1));
            vm = fmaxf(vm, __shfl_xor(vm, 2));
            vm = fmaxf(vm, __shfl_xor(vm, 4));
            vm = fmaxf(vm, __shfl_xor(vm, 8));
            float mn = fmaxf(mrow[jj], vm);
            float scale = __expf(mrow[jj] - mn);
            float ps = 0.f;
            #pragma unroll
            for (int nf = 0; nf < 4; ++nf) {
                float p = __expf(s[nf][jj] - mn);
                s[nf][jj] = p;
                ps += p;
            }
            ps += __shfl_xor(ps, 1); ps += __shfl_xor(ps, 2);
            ps += __shfl_xor(ps, 4); ps += __shfl_xor(ps, 8);
            lrow[jj] = lrow[jj] * scale + ps;
            mrow[jj] = mn;
            #pragma unroll
            for (int nf = 0; nf < 8; ++nf) o[nf][jj] *= scale;
        }
        #pragma unroll
        for (int nf = 0; nf < 4; ++nf)
            #pragma unroll
            for (int jj = 0; jj < 4; ++jj)
                Ps[wave][l16 * 4 + jj][nf * 16 + l15] = f2bf(s[nf][jj]);
        __syncthreads();
        #pragma unroll
        for (int kc = 0; kc < 2; ++kc) {
            s8v pf = *reinterpret_cast<const s8v*>(&Ps[wave][l15][kc * 32 + l16 * 8]);
            #pragma unroll
            for (int nf = 0; nf < 8; ++nf) {
                s8v vf = *reinterpret_cast<const s8v*>(&Vt[nf * 16 + l15][kc * 32 + l16 * 8]);
                o[nf] = __builtin_amdgcn_mfma_f32_16x16x32_bf16(as_bf(pf), as_bf(vf), o[nf], 0, 0, 0);
            }
        }
    }
    #pragma unroll
    for (int nf = 0; nf < 8; ++nf)
        #pragma unroll
        for (int jj = 0; jj < 4; ++jj) {
            float v = o[nf][jj] / lrow[jj];
            ao[(size_t)(b * Tt + qr0 + l16 * 4 + jj) * Hh + hh * VD + nf * 16 + l15] = f2bf(v);
        }
}

// ---------------- residual + LayerNorm ----------------
__global__ __launch_bounds__(256)
void k_ln(const unsigned short* __restrict__ aop, const unsigned short* __restrict__ rnn,
          const float* __restrict__ g, const float* __restrict__ be,
          unsigned short* __restrict__ y) {
    const int row = blockIdx.x, tid = threadIdx.x;
    const int lane = tid & 63, wave = tid >> 6;
    const size_t base = (size_t)row * Hh;
    s8v a8 = *reinterpret_cast<const s8v*>(aop + base + tid * 8);
    s8v r8 = *reinterpret_cast<const s8v*>(rnn + base + tid * 8);
    float v[8]; float s = 0.f;
    #pragma unroll
    for (int i = 0; i < 8; ++i) {
        v[i] = bf2f((unsigned short)a8[i]) + bf2f((unsigned short)r8[i]);
        s += v[i];
    }
    #pragma unroll
    for (int d = 32; d >= 1; d >>= 1) s += __shfl_xor(s, d);
    __shared__ float red[8];
    if (lane == 0) red[wave] = s;
    __syncthreads();
    float mu = (red[0] + red[1] + red[2] + red[3]) * (1.0f / Hh);
    float d2 = 0.f;
    #pragma unroll
    for (int i = 0; i < 8; ++i) { float dd = v[i] - mu; d2 += dd * dd; }
    #pragma unroll
    for (int d = 32; d >= 1; d >>= 1) d2 += __shfl_xor(d2, d);
    if (lane == 0) red[4 + wave] = d2;
    __syncthreads();
    float var = (red[4] + red[5] + red[6] + red[7]) * (1.0f / Hh);
    float rstd = rsqrtf(var + 1e-5f);
    s8v outv;
    #pragma unroll
    for (int i = 0; i < 8; ++i) {
        int c = tid * 8 + i;
        float ov = (v[i] - mu) * rstd * g[c] + be[c];
        outv[i] = (short)f2bf(ov);
    }
    *reinterpret_cast<s8v*>(y + base + tid * 8) = outv;
}

extern "C" void kernel_launch(void* const* d_in, const int* in_sizes, int n_in,
                              void* d_out, int out_size, void* d_ws, size_t ws_size,
                              hipStream_t stream) {
    const int*   tokens = (const int*)  d_in[0];
    const float* E    = (const float*)d_in[1];
    const float* Wi   = (const float*)d_in[2];
    const float* bi   = (const float*)d_in[3];
    const float* Wh   = (const float*)d_in[4];
    const float* Wo   = (const float*)d_in[5];
    const float* bo   = (const float*)d_in[6];
    const float* Wqkv = (const float*)d_in[7];
    const float* Wao  = (const float*)d_in[8];
    const float* bao  = (const float*)d_in[9];
    const float* lng  = (const float*)d_in[10];
    const float* lnb  = (const float*)d_in[11];
    const float* Wlm  = (const float*)d_in[12];
    const float* blm  = (const float*)d_in[13];
    float* out = (float*)d_out;

    char* ws = (char*)d_ws;
    size_t off = 0;
    auto alloc = [&](size_t bytes) -> void* {
        void* p = ws + off;
        off += (bytes + 255) & ~(size_t)255;
        return p;
    };
    unsigned short* bWi   = (unsigned short*)alloc((size_t)Hh * DE * 2);
    unsigned short* bWo   = (unsigned short*)alloc((size_t)Hh * Hh * 2);
    unsigned short* bWqkv = (unsigned short*)alloc((size_t)QKVC * Hh * 2);
    unsigned short* bWao  = (unsigned short*)alloc((size_t)Hh * Hh * 2);
    unsigned short* bWlm  = (unsigned short*)alloc((size_t)Vv * Hh * 2);
    unsigned short* bWh   = (unsigned short*)alloc((size_t)Hh * Hh * 2);
    unsigned short* xb    = (unsigned short*)alloc((size_t)Bb * Tt * DE * 2);
    float*          xi    = (float*)         alloc((size_t)Bb * Tt * Hh * 4);
    unsigned short* hsb   = (unsigned short*)alloc((size_t)Bb * Tt * Hh * 2);
    unsigned short* rnn   = (unsigned short*)alloc((size_t)Bb * Tt * Hh * 2);
    unsigned short* qkvb  = (unsigned short*)alloc((size_t)Bb * Tt * QKVC * 2);
    unsigned short* aob   = (unsigned short*)alloc((size_t)Bb * Tt * Hh * 2);
    unsigned short* aopb  = (unsigned short*)alloc((size_t)Bb * Tt * Hh * 2);
    unsigned short* yb    = (unsigned short*)alloc((size_t)Bb * Tt * Hh * 2);

    // hseq (32MB, write-once per step) aliases qkvb's space: qkvb (50MB) is
    // only written by the qkv GEMM, which runs strictly after k_scan completes.
    float* hseq = (float*)qkvb;
    hipMemsetAsync(hseq, 0xFF, (size_t)Tt * 2 * Hh * 4, stream);   // sentinel poison

    auto cvt = [&](const float* src, unsigned short* dst, size_t n) {
        int n4 = (int)(n / 4);
        k_cvt<<<(n4 + 255) / 256, 256, 0, stream>>>(src, dst, n4);
    };
    cvt(Wi,   bWi,   (size_t)Hh * DE);
    cvt(Wo,   bWo,   (size_t)Hh * Hh);
    cvt(Wqkv, bWqkv, (size_t)QKVC * Hh);
    cvt(Wao,  bWao,  (size_t)Hh * Hh);
    cvt(Wlm,  bWlm,  (size_t)Vv * Hh);
    cvt(Wh,   bWh,   (size_t)Hh * Hh);

    k_embed<<<Bb * Tt, 256, 0, stream>>>(tokens, E, xb);

    // xi = x @ Wi^T + bi   (fp32 out)
    k_gemm<1, 1><<<dim3(Hh / 128, (Bb * Tt) / 128), 256, 0, stream>>>(xb, bWi, bi, xi, Bb * Tt, Hh, DE);
    // sequential RNN scan -> hs (bf16), bf16 register-resident weights
    k_scan<<<128, 512, 0, stream>>>(bWh, xi, hsb, hseq);
    // rnn_out = hs @ Wo^T + bo  (bf16)
    k_gemm<0, 1><<<dim3(Hh / 128, (Bb * Tt) / 128), 256, 0, stream>>>(hsb, bWo, bo, rnn, Bb * Tt, Hh, Hh);
    // qkv = rnn_out @ Wqkv^T    (bf16, no bias)
    k_gemm<0, 0><<<dim3(QKVC / 128, (Bb * Tt) / 128), 256, 0, stream>>>(rnn, bWqkv, nullptr, qkvb, Bb * Tt, QKVC, Hh);
    // causal attention
    k_attn<<<dim3(Tt / 64, Bb * NH), 256, 0, stream>>>(qkvb, aob);
    // ao @ Wao^T + bao          (bf16)
    k_gemm<0, 1><<<dim3(Hh / 128, (Bb * Tt) / 128), 256, 0, stream>>>(aob, bWao, bao, aopb, Bb * Tt, Hh, Hh);
    // y = LN(aop + rnn_out)
    k_ln<<<Bb * Tt, 256, 0, stream>>>(aopb, rnn, lng, lnb, yb);
    // logits = y @ Wlm^T + blm  (fp32 out)
    k_gemm<1, 1><<<dim3(Vv / 128, (Bb * Tt) / 128), 256, 0, stream>>>(yb, bWlm, blm, out, Bb * Tt, Vv, Hh);
}